// Round 1
// baseline (281.428 us; speedup 1.0000x reference)
//
#include <hip/hip_runtime.h>

typedef __attribute__((ext_vector_type(4))) float  f32x4;
typedef __attribute__((ext_vector_type(8))) short  s16x8;

// ---------- helpers ----------
__device__ __forceinline__ unsigned short f2bf(float f) {
    union { float f; unsigned u; } v; v.f = f;
    unsigned u = v.u + 0x7fffu + ((v.u >> 16) & 1u);   // RNE
    return (unsigned short)(u >> 16);
}

__device__ __forceinline__ void gl_lds16(const unsigned short* g, unsigned short* l) {
    __builtin_amdgcn_global_load_lds(
        (const __attribute__((address_space(1))) void*)g,
        (__attribute__((address_space(3))) void*)l, 16, 0, 0);
}

__device__ __forceinline__ f32x4 mfma16(s16x8 a, s16x8 b, f32x4 c) {
    return __builtin_amdgcn_mfma_f32_16x16x32_bf16(a, b, c, 0, 0, 0);
}

// ---------- fp32 -> bf16 convert ----------
__global__ void k_convert(const float* __restrict__ s, unsigned short* __restrict__ d, int n4) {
    int i = blockIdx.x * 256 + threadIdx.x;
    if (i >= n4) return;
    float4 f = reinterpret_cast<const float4*>(s)[i];
    ushort4 o;
    o.x = f2bf(f.x); o.y = f2bf(f.y); o.z = f2bf(f.z); o.w = f2bf(f.w);
    reinterpret_cast<ushort4*>(d)[i] = o;
}

// ---------- RoPE cos/sin table (fp32, matches reference fp32 math) ----------
__global__ void k_rope_table(float* __restrict__ ct, float* __restrict__ st) {
    int i = blockIdx.x * 256 + threadIdx.x;      // 2048*64
    int s = i >> 6, d = i & 63;
    float invf = powf(10000.0f, -(float)(d & 31) * (1.0f / 32.0f));
    float ang = (float)s * invf;
    float sv, cv;
    sincosf(ang, &sv, &cv);
    ct[i] = cv; st[i] = sv;
}

// ---------- fused QKV projection GEMM (bf16 MFMA) ----------
// z=0: Q = X*Wq^T (+RoPE, *0.125) -> [B,H,S,D]
// z=1: K = X*Wk^T (+RoPE)         -> [B,H,S,D]
// z=2: V^T = Wv*X^T               -> [B,H,D,S]   (swapped operands)
__global__ __launch_bounds__(256) void k_gemm_qkv(
    const unsigned short* __restrict__ Xb,
    const unsigned short* __restrict__ Wqb,
    const unsigned short* __restrict__ Wkb,
    const unsigned short* __restrict__ Wvb,
    const float* __restrict__ ct, const float* __restrict__ st,
    unsigned short* __restrict__ Qo, unsigned short* __restrict__ Ko,
    unsigned short* __restrict__ Vt)
{
    __shared__ __attribute__((aligned(16))) unsigned short As[128 * 32];
    __shared__ __attribute__((aligned(16))) unsigned short Bs[128 * 32];
    const int z = blockIdx.z;
    const int tid = threadIdx.x;
    const int lane = tid & 63;
    const int w  = tid >> 6;
    const int wm = (w >> 1) * 64, wn = (w & 1) * 64;
    const int r  = lane & 15, rg = lane >> 4;

    const unsigned short *Ap, *Bp;
    int m0, n0;
    if (z < 2) { Ap = Xb;  Bp = z ? Wkb : Wqb; m0 = blockIdx.x * 128; n0 = blockIdx.y * 128; }
    else       { Ap = Wvb; Bp = Xb;            m0 = blockIdx.y * 128; n0 = blockIdx.x * 128; }

    f32x4 acc[4][4];
    const f32x4 zf = {0.f, 0.f, 0.f, 0.f};
    #pragma unroll
    for (int i = 0; i < 4; i++)
        #pragma unroll
        for (int j = 0; j < 4; j++) acc[i][j] = zf;

    const unsigned short* ga = Ap + (size_t)(m0 + (tid >> 2)) * 1024 + (tid & 3) * 8;
    const unsigned short* gb = Bp + (size_t)(n0 + (tid >> 2)) * 1024 + (tid & 3) * 8;

    for (int k0 = 0; k0 < 1024; k0 += 32) {
        gl_lds16(ga + k0,             As + tid * 8);
        gl_lds16(ga + k0 + 64 * 1024, As + 2048 + tid * 8);
        gl_lds16(gb + k0,             Bs + tid * 8);
        gl_lds16(gb + k0 + 64 * 1024, Bs + 2048 + tid * 8);
        __syncthreads();
        s16x8 af[4], bfr[4];
        #pragma unroll
        for (int mi = 0; mi < 4; mi++) af[mi]  = *(const s16x8*)&As[(wm + mi * 16 + r) * 32 + rg * 8];
        #pragma unroll
        for (int ni = 0; ni < 4; ni++) bfr[ni] = *(const s16x8*)&Bs[(wn + ni * 16 + r) * 32 + rg * 8];
        #pragma unroll
        for (int mi = 0; mi < 4; mi++)
            #pragma unroll
            for (int ni = 0; ni < 4; ni++)
                acc[mi][ni] = mfma16(af[mi], bfr[ni], acc[mi][ni]);
        __syncthreads();
    }

    if (z < 2) {
        unsigned short* Out = z ? Ko : Qo;
        const float qscale = z ? 1.0f : 0.125f;       // fold 1/sqrt(64) into Q
        #pragma unroll
        for (int mi = 0; mi < 4; mi++)
            #pragma unroll
            for (int ni = 0; ni < 4; ni++)
                #pragma unroll
                for (int rr = 0; rr < 4; rr++) {
                    float v = acc[mi][ni][rr];
                    float vp = __shfl_xor(v, 1);      // partner within interleaved pair
                    int m = m0 + wm + mi * 16 + rg * 4 + rr;
                    int e = n0 + wn + ni * 16 + r;
                    int s = m & 2047, d = e & 63;
                    float c = ct[(s << 6) + d], sn = st[(s << 6) + d];
                    float sgn = (e & 1) ? 1.0f : -1.0f;
                    v = fmaf(v, c, sgn * vp * sn) * qscale;
                    int b = m >> 11, h = e >> 6;
                    Out[(((size_t)(b * 16 + h) * 2048 + s) << 6) + d] = f2bf(v);
                }
    } else {
        #pragma unroll
        for (int mi = 0; mi < 4; mi++)
            #pragma unroll
            for (int ni = 0; ni < 4; ni++)
                #pragma unroll
                for (int rr = 0; rr < 4; rr++) {
                    int e  = m0 + wm + mi * 16 + rg * 4 + rr;   // Wv output row
                    int mm = n0 + wn + ni * 16 + r;             // token index
                    int b = mm >> 11, s = mm & 2047, h = e >> 6, d = e & 63;
                    Vt[((size_t)(b * 16 + h) * 64 + d) * 2048 + s] = f2bf(acc[mi][ni][rr]);
                }
    }
}

// ---------- flash attention (non-causal), bf16 MFMA, fp32 softmax ----------
// Q,K: [B,H,S,D] bf16 (Q pre-scaled by 0.125); Vt: [B,H,D,S] bf16
// AO: [B*S, 1024] bf16
__global__ __launch_bounds__(256) void k_attn(
    const unsigned short* __restrict__ Q,
    const unsigned short* __restrict__ K,
    const unsigned short* __restrict__ Vt,
    unsigned short* __restrict__ AO)
{
    __shared__ __attribute__((aligned(16))) unsigned short Ks0[64 * 32], Ks1[64 * 32];
    __shared__ __attribute__((aligned(16))) unsigned short Vs0[64 * 32], Vs1[64 * 32];
    __shared__ __attribute__((aligned(16))) unsigned short Ps0[4][32 * 32], Ps1[4][32 * 32];
    const int bh = blockIdx.y;
    const int q0 = blockIdx.x * 128;
    const int tid = threadIdx.x, lane = tid & 63, w = tid >> 6;
    const int r = lane & 15, rg = lane >> 4;
    const unsigned short* Qp = Q  + (size_t)bh * 2048 * 64;
    const unsigned short* Kp = K  + (size_t)bh * 2048 * 64;
    const unsigned short* Vp = Vt + (size_t)bh * 64 * 2048;
    const int qw = q0 + w * 32;

    s16x8 qf[2][2];
    #pragma unroll
    for (int mi = 0; mi < 2; mi++)
        #pragma unroll
        for (int kk = 0; kk < 2; kk++)
            qf[mi][kk] = *(const s16x8*)&Qp[(size_t)(qw + mi * 16 + r) * 64 + kk * 32 + rg * 8];

    const f32x4 zf = {0.f, 0.f, 0.f, 0.f};
    f32x4 oacc[2][4];
    float mrun[2][4], lrun[2][4];
    #pragma unroll
    for (int mi = 0; mi < 2; mi++) {
        #pragma unroll
        for (int ni = 0; ni < 4; ni++) oacc[mi][ni] = zf;
        #pragma unroll
        for (int rr = 0; rr < 4; rr++) { mrun[mi][rr] = -1e30f; lrun[mi][rr] = 0.f; }
    }

    const unsigned short* gk = Kp + (size_t)(tid >> 2) * 64 + (tid & 3) * 8;
    const unsigned short* gv = Vp + (size_t)(tid >> 2) * 2048 + (tid & 3) * 8;
    unsigned short* pw0 = Ps0[w];
    unsigned short* pw1 = Ps1[w];

    for (int kt = 0; kt < 2048; kt += 64) {
        gl_lds16(gk + (size_t)kt * 64,      Ks0 + tid * 8);
        gl_lds16(gk + (size_t)kt * 64 + 32, Ks1 + tid * 8);
        gl_lds16(gv + kt,                   Vs0 + tid * 8);
        gl_lds16(gv + kt + 32,              Vs1 + tid * 8);
        __syncthreads();

        // QK^T
        f32x4 sacc[2][4];
        #pragma unroll
        for (int mi = 0; mi < 2; mi++)
            #pragma unroll
            for (int ni = 0; ni < 4; ni++) sacc[mi][ni] = zf;
        {
            s16x8 kf0[4], kf1[4];
            #pragma unroll
            for (int ni = 0; ni < 4; ni++) {
                kf0[ni] = *(const s16x8*)&Ks0[(ni * 16 + r) * 32 + rg * 8];
                kf1[ni] = *(const s16x8*)&Ks1[(ni * 16 + r) * 32 + rg * 8];
            }
            #pragma unroll
            for (int mi = 0; mi < 2; mi++)
                #pragma unroll
                for (int ni = 0; ni < 4; ni++) {
                    sacc[mi][ni] = mfma16(qf[mi][0], kf0[ni], sacc[mi][ni]);
                    sacc[mi][ni] = mfma16(qf[mi][1], kf1[ni], sacc[mi][ni]);
                }
        }

        // online softmax
        float alpha[2][4];
        #pragma unroll
        for (int mi = 0; mi < 2; mi++)
            #pragma unroll
            for (int rr = 0; rr < 4; rr++) {
                float t = fmaxf(fmaxf(sacc[mi][0][rr], sacc[mi][1][rr]),
                                fmaxf(sacc[mi][2][rr], sacc[mi][3][rr]));
                t = fmaxf(t, __shfl_xor(t, 1));
                t = fmaxf(t, __shfl_xor(t, 2));
                t = fmaxf(t, __shfl_xor(t, 4));
                t = fmaxf(t, __shfl_xor(t, 8));
                float nm = fmaxf(mrun[mi][rr], t);
                float a = __expf(mrun[mi][rr] - nm);
                alpha[mi][rr] = a;
                mrun[mi][rr] = nm;
                float rs = 0.f;
                #pragma unroll
                for (int ni = 0; ni < 4; ni++) {
                    float p = __expf(sacc[mi][ni][rr] - nm);
                    sacc[mi][ni][rr] = p;
                    rs += p;
                }
                rs += __shfl_xor(rs, 1);
                rs += __shfl_xor(rs, 2);
                rs += __shfl_xor(rs, 4);
                rs += __shfl_xor(rs, 8);
                lrun[mi][rr] = lrun[mi][rr] * a + rs;
            }

        // P -> LDS (bf16), per-wave buffers
        #pragma unroll
        for (int mi = 0; mi < 2; mi++)
            #pragma unroll
            for (int ni = 0; ni < 4; ni++)
                #pragma unroll
                for (int rr = 0; rr < 4; rr++) {
                    int q = mi * 16 + rg * 4 + rr;
                    int c = (ni & 1) * 16 + r;
                    unsigned short pb = f2bf(sacc[mi][ni][rr]);
                    if (ni < 2) pw0[q * 32 + c] = pb;
                    else        pw1[q * 32 + c] = pb;
                }
        asm volatile("s_waitcnt lgkmcnt(0)" ::: "memory");

        // rescale O
        #pragma unroll
        for (int mi = 0; mi < 2; mi++)
            #pragma unroll
            for (int ni = 0; ni < 4; ni++)
                #pragma unroll
                for (int rr = 0; rr < 4; rr++)
                    oacc[mi][ni][rr] *= alpha[mi][rr];

        // PV
        {
            s16x8 pa0[2], pa1[2], vf0[4], vf1[4];
            #pragma unroll
            for (int mi = 0; mi < 2; mi++) {
                pa0[mi] = *(const s16x8*)&pw0[(mi * 16 + r) * 32 + rg * 8];
                pa1[mi] = *(const s16x8*)&pw1[(mi * 16 + r) * 32 + rg * 8];
            }
            #pragma unroll
            for (int ni = 0; ni < 4; ni++) {
                vf0[ni] = *(const s16x8*)&Vs0[(ni * 16 + r) * 32 + rg * 8];
                vf1[ni] = *(const s16x8*)&Vs1[(ni * 16 + r) * 32 + rg * 8];
            }
            #pragma unroll
            for (int mi = 0; mi < 2; mi++)
                #pragma unroll
                for (int ni = 0; ni < 4; ni++) {
                    oacc[mi][ni] = mfma16(pa0[mi], vf0[ni], oacc[mi][ni]);
                    oacc[mi][ni] = mfma16(pa1[mi], vf1[ni], oacc[mi][ni]);
                }
        }
        __syncthreads();
    }

    const int b = bh >> 4, h = bh & 15;
    #pragma unroll
    for (int mi = 0; mi < 2; mi++)
        #pragma unroll
        for (int rr = 0; rr < 4; rr++) {
            float inv = 1.0f / lrun[mi][rr];
            int qrow = qw + mi * 16 + rg * 4 + rr;
            size_t base = ((size_t)(b * 2048 + qrow)) * 1024 + h * 64;
            #pragma unroll
            for (int ni = 0; ni < 4; ni++)
                AO[base + ni * 16 + r] = f2bf(oacc[mi][ni][rr] * inv);
        }
}

// ---------- output projection GEMM: Out = AO * Wo^T (fp32 out) ----------
__global__ __launch_bounds__(256) void k_gemm_out(
    const unsigned short* __restrict__ AOb,
    const unsigned short* __restrict__ Wob,
    float* __restrict__ Out)
{
    __shared__ __attribute__((aligned(16))) unsigned short As[128 * 32];
    __shared__ __attribute__((aligned(16))) unsigned short Bs[128 * 32];
    const int tid = threadIdx.x;
    const int lane = tid & 63;
    const int w  = tid >> 6;
    const int wm = (w >> 1) * 64, wn = (w & 1) * 64;
    const int r  = lane & 15, rg = lane >> 4;
    const int m0 = blockIdx.x * 128, n0 = blockIdx.y * 128;

    f32x4 acc[4][4];
    const f32x4 zf = {0.f, 0.f, 0.f, 0.f};
    #pragma unroll
    for (int i = 0; i < 4; i++)
        #pragma unroll
        for (int j = 0; j < 4; j++) acc[i][j] = zf;

    const unsigned short* ga = AOb + (size_t)(m0 + (tid >> 2)) * 1024 + (tid & 3) * 8;
    const unsigned short* gb = Wob + (size_t)(n0 + (tid >> 2)) * 1024 + (tid & 3) * 8;

    for (int k0 = 0; k0 < 1024; k0 += 32) {
        gl_lds16(ga + k0,             As + tid * 8);
        gl_lds16(ga + k0 + 64 * 1024, As + 2048 + tid * 8);
        gl_lds16(gb + k0,             Bs + tid * 8);
        gl_lds16(gb + k0 + 64 * 1024, Bs + 2048 + tid * 8);
        __syncthreads();
        s16x8 af[4], bfr[4];
        #pragma unroll
        for (int mi = 0; mi < 4; mi++) af[mi]  = *(const s16x8*)&As[(wm + mi * 16 + r) * 32 + rg * 8];
        #pragma unroll
        for (int ni = 0; ni < 4; ni++) bfr[ni] = *(const s16x8*)&Bs[(wn + ni * 16 + r) * 32 + rg * 8];
        #pragma unroll
        for (int mi = 0; mi < 4; mi++)
            #pragma unroll
            for (int ni = 0; ni < 4; ni++)
                acc[mi][ni] = mfma16(af[mi], bfr[ni], acc[mi][ni]);
        __syncthreads();
    }

    #pragma unroll
    for (int mi = 0; mi < 4; mi++)
        #pragma unroll
        for (int ni = 0; ni < 4; ni++)
            #pragma unroll
            for (int rr = 0; rr < 4; rr++) {
                int m = m0 + wm + mi * 16 + rg * 4 + rr;
                int e = n0 + wn + ni * 16 + r;
                Out[(size_t)m * 1024 + e] = acc[mi][ni][rr];
            }
}

// ---------- launcher ----------
extern "C" void kernel_launch(void* const* d_in, const int* in_sizes, int n_in,
                              void* d_out, int out_size, void* d_ws, size_t ws_size,
                              hipStream_t stream) {
    const float* X  = (const float*)d_in[0];
    const float* Wq = (const float*)d_in[1];
    const float* Wk = (const float*)d_in[2];
    const float* Wv = (const float*)d_in[3];
    const float* Wo = (const float*)d_in[4];
    float* Out = (float*)d_out;
    char* ws = (char*)d_ws;

    unsigned short* Xb   = (unsigned short*)(ws);                 //  8,388,608
    unsigned short* Wqb  = (unsigned short*)(ws + 8388608);       //  2,097,152
    unsigned short* Wkb  = (unsigned short*)(ws + 10485760);
    unsigned short* Wvb  = (unsigned short*)(ws + 12582912);
    unsigned short* Wob  = (unsigned short*)(ws + 14680064);
    unsigned short* Qb   = (unsigned short*)(ws + 16777216);      //  8,388,608
    unsigned short* Kb   = (unsigned short*)(ws + 25165824);
    unsigned short* Vtb  = (unsigned short*)(ws + 33554432);
    unsigned short* AOb  = (unsigned short*)(ws + 41943040);
    float*          cosT = (float*)(ws + 50331648);               //  524,288
    float*          sinT = (float*)(ws + 50855936);

    k_convert<<<4096, 256, 0, stream>>>(X,  Xb,  1048576);
    k_convert<<<1024, 256, 0, stream>>>(Wq, Wqb, 262144);
    k_convert<<<1024, 256, 0, stream>>>(Wk, Wkb, 262144);
    k_convert<<<1024, 256, 0, stream>>>(Wv, Wvb, 262144);
    k_convert<<<1024, 256, 0, stream>>>(Wo, Wob, 262144);
    k_rope_table<<<512, 256, 0, stream>>>(cosT, sinT);
    k_gemm_qkv<<<dim3(32, 8, 3), 256, 0, stream>>>(Xb, Wqb, Wkb, Wvb, cosT, sinT, Qb, Kb, Vtb);
    k_attn<<<dim3(16, 32), 256, 0, stream>>>(Qb, Kb, Vtb, AOb);
    k_gemm_out<<<dim3(32, 8), 256, 0, stream>>>(AOb, Wob, Out);
}

// Round 5
// 226.411 us; speedup vs baseline: 1.2430x; 1.2430x over previous
//
#include <hip/hip_runtime.h>

typedef __attribute__((ext_vector_type(4)))  float  f32x4;
typedef __attribute__((ext_vector_type(16))) float  f32x16;
typedef __attribute__((ext_vector_type(8)))  short  s16x8;

// ---------- helpers ----------
__device__ __forceinline__ unsigned short f2bf(float f) {
    union { float f; unsigned u; } v; v.f = f;
    unsigned u = v.u + 0x7fffu + ((v.u >> 16) & 1u);   // RNE
    return (unsigned short)(u >> 16);
}

__device__ __forceinline__ unsigned cvtpk(float lo, float hi_) {
    unsigned r;
    asm("v_cvt_pk_bf16_f32 %0, %1, %2" : "=v"(r) : "v"(lo), "v"(hi_));
    return r;
}

__device__ __forceinline__ void gl_lds16(const unsigned short* g, unsigned short* l) {
    __builtin_amdgcn_global_load_lds(
        (const __attribute__((address_space(1))) void*)g,
        (__attribute__((address_space(3))) void*)l, 16, 0, 0);
}

__device__ __forceinline__ f32x4 mfma16(s16x8 a, s16x8 b, f32x4 c) {
    return __builtin_amdgcn_mfma_f32_16x16x32_bf16(a, b, c, 0, 0, 0);
}
__device__ __forceinline__ f32x16 mfma32(s16x8 a, s16x8 b, f32x16 c) {
    return __builtin_amdgcn_mfma_f32_32x32x16_bf16(a, b, c, 0, 0, 0);
}

// ---------- fp32 -> bf16 convert ----------
__global__ void k_convert(const float* __restrict__ s, unsigned short* __restrict__ d, int n4) {
    int i = blockIdx.x * 256 + threadIdx.x;
    if (i >= n4) return;
    float4 f = reinterpret_cast<const float4*>(s)[i];
    ushort4 o;
    o.x = f2bf(f.x); o.y = f2bf(f.y); o.z = f2bf(f.z); o.w = f2bf(f.w);
    reinterpret_cast<ushort4*>(d)[i] = o;
}

// ---------- RoPE cos/sin table ----------
__global__ void k_rope_table(float* __restrict__ ct, float* __restrict__ st) {
    int i = blockIdx.x * 256 + threadIdx.x;      // 2048*64
    int s = i >> 6, d = i & 63;
    float invf = powf(10000.0f, -(float)(d & 31) * (1.0f / 32.0f));
    float ang = (float)s * invf;
    float sv, cv;
    sincosf(ang, &sv, &cv);
    ct[i] = cv; st[i] = sv;
}

// ---------- fused QKV projection GEMM (bf16 MFMA) ----------
__global__ __launch_bounds__(256) void k_gemm_qkv(
    const unsigned short* __restrict__ Xb,
    const unsigned short* __restrict__ Wqb,
    const unsigned short* __restrict__ Wkb,
    const unsigned short* __restrict__ Wvb,
    const float* __restrict__ ct, const float* __restrict__ st,
    unsigned short* __restrict__ Qo, unsigned short* __restrict__ Ko,
    unsigned short* __restrict__ Vt)
{
    __shared__ __attribute__((aligned(16))) unsigned short As[128 * 32];
    __shared__ __attribute__((aligned(16))) unsigned short Bs[128 * 32];
    const int z = blockIdx.z;
    const int tid = threadIdx.x;
    const int lane = tid & 63;
    const int w  = tid >> 6;
    const int wm = (w >> 1) * 64, wn = (w & 1) * 64;
    const int r  = lane & 15, rg = lane >> 4;

    const unsigned short *Ap, *Bp;
    int m0, n0;
    if (z < 2) { Ap = Xb;  Bp = z ? Wkb : Wqb; m0 = blockIdx.x * 128; n0 = blockIdx.y * 128; }
    else       { Ap = Wvb; Bp = Xb;            m0 = blockIdx.y * 128; n0 = blockIdx.x * 128; }

    f32x4 acc[4][4];
    const f32x4 zf = {0.f, 0.f, 0.f, 0.f};
    #pragma unroll
    for (int i = 0; i < 4; i++)
        #pragma unroll
        for (int j = 0; j < 4; j++) acc[i][j] = zf;

    const unsigned short* ga = Ap + (size_t)(m0 + (tid >> 2)) * 1024 + (tid & 3) * 8;
    const unsigned short* gb = Bp + (size_t)(n0 + (tid >> 2)) * 1024 + (tid & 3) * 8;

    for (int k0 = 0; k0 < 1024; k0 += 32) {
        gl_lds16(ga + k0,             As + tid * 8);
        gl_lds16(ga + k0 + 64 * 1024, As + 2048 + tid * 8);
        gl_lds16(gb + k0,             Bs + tid * 8);
        gl_lds16(gb + k0 + 64 * 1024, Bs + 2048 + tid * 8);
        __syncthreads();
        s16x8 af[4], bfr[4];
        #pragma unroll
        for (int mi = 0; mi < 4; mi++) af[mi]  = *(const s16x8*)&As[(wm + mi * 16 + r) * 32 + rg * 8];
        #pragma unroll
        for (int ni = 0; ni < 4; ni++) bfr[ni] = *(const s16x8*)&Bs[(wn + ni * 16 + r) * 32 + rg * 8];
        #pragma unroll
        for (int mi = 0; mi < 4; mi++)
            #pragma unroll
            for (int ni = 0; ni < 4; ni++)
                acc[mi][ni] = mfma16(af[mi], bfr[ni], acc[mi][ni]);
        __syncthreads();
    }

    if (z < 2) {
        unsigned short* Out = z ? Ko : Qo;
        const float qscale = z ? 1.0f : 0.125f;
        #pragma unroll
        for (int mi = 0; mi < 4; mi++)
            #pragma unroll
            for (int ni = 0; ni < 4; ni++)
                #pragma unroll
                for (int rr = 0; rr < 4; rr++) {
                    float v = acc[mi][ni][rr];
                    float vp = __shfl_xor(v, 1);
                    int m = m0 + wm + mi * 16 + rg * 4 + rr;
                    int e = n0 + wn + ni * 16 + r;
                    int s = m & 2047, d = e & 63;
                    float c = ct[(s << 6) + d], sn = st[(s << 6) + d];
                    float sgn = (e & 1) ? 1.0f : -1.0f;
                    v = fmaf(v, c, sgn * vp * sn) * qscale;
                    int b = m >> 11, h = e >> 6;
                    Out[(((size_t)(b * 16 + h) * 2048 + s) << 6) + d] = f2bf(v);
                }
    } else {
        #pragma unroll
        for (int mi = 0; mi < 4; mi++)
            #pragma unroll
            for (int ni = 0; ni < 4; ni++)
                #pragma unroll
                for (int rr = 0; rr < 4; rr++) {
                    int e  = m0 + wm + mi * 16 + rg * 4 + rr;
                    int mm = n0 + wn + ni * 16 + r;
                    int b = mm >> 11, s = mm & 2047, h = e >> 6, d = e & 63;
                    Vt[((size_t)(b * 16 + h) * 64 + d) * 2048 + s] = f2bf(acc[mi][ni][rr]);
                }
    }
}

// ---------- flash attention, 8-wave 32x32 swapped-operand structure ----------
// Q,K: [B,H,S=2048,D=64] bf16 (Q pre-scaled by 0.125); Vt: [B,H,D,S] bf16
// AO:  [B*S, 1024] bf16
// QK^T swapped: mfma(K,Q) -> S^T: q=lane&31, kv=(reg&3)+8*(reg>>2)+4*hi (+32 for s1)
// PV  swapped: mfma(Vt,P^T) -> O^T: q=lane&31, d over regs -> per-lane softmax state.
__global__ __launch_bounds__(512, 2) void k_attn(
    const unsigned short* __restrict__ Q,
    const unsigned short* __restrict__ K,
    const unsigned short* __restrict__ Vt,
    unsigned short* __restrict__ AO)
{
    __shared__ __attribute__((aligned(16))) unsigned short Ks[2][64 * 64];
    __shared__ __attribute__((aligned(16))) unsigned short Vs[2][64 * 64];
    const int bh = blockIdx.y;
    const int q0 = blockIdx.x * 256;
    const int tid = threadIdx.x, lane = tid & 63, w = tid >> 6;
    const int ln31 = lane & 31, hi = lane >> 5;
    const int swz = (ln31 & 7) << 3;            // element-index XOR (16B granules)
    const unsigned short* Qp = Q  + (size_t)bh * 2048 * 64;
    const unsigned short* Kp = K  + (size_t)bh * 2048 * 64;
    const unsigned short* Vp = Vt + (size_t)bh * 64 * 2048;

    // Q B-fragments: lane=q (ln31), k = ds*16 + hi*8 + j
    s16x8 qf[4];
    #pragma unroll
    for (int ds = 0; ds < 4; ds++)
        qf[ds] = *(const s16x8*)&Qp[(size_t)(q0 + w * 32 + ln31) * 64 + ds * 16 + hi * 8];

    f32x16 o0, o1;
    #pragma unroll
    for (int r = 0; r < 16; r++) { o0[r] = 0.f; o1[r] = 0.f; }
    float mrun = -1e30f, lrun = 0.f;

    // staging: thread t -> one 16B chunk; LDS dest linear, global source pre-swizzled
    const int srow = tid >> 3;
    const int scol = ((tid & 7) * 8) ^ ((srow & 7) << 3);
    const unsigned short* gk = Kp + (size_t)srow * 64   + scol;
    const unsigned short* gv = Vp + (size_t)srow * 2048 + scol;
    const int t8 = tid * 8;

    gl_lds16(gk, &Ks[0][t8]);
    gl_lds16(gv, &Vs[0][t8]);
    asm volatile("s_waitcnt vmcnt(0)" ::: "memory");
    __syncthreads();

    int cur = 0;
    for (int t = 0; t < 32; ++t) {
        if (t < 31) {  // stage next tile; the loop-end __syncthreads drains vmcnt
            gl_lds16(gk + (size_t)(t + 1) * 4096, &Ks[cur ^ 1][t8]);
            gl_lds16(gv + (size_t)(t + 1) * 64,   &Vs[cur ^ 1][t8]);
        }
        const unsigned short* Kb = Ks[cur];
        const unsigned short* Vb = Vs[cur];

        // QK^T (swapped): S^T[kv][q]
        f32x16 s0, s1;
        #pragma unroll
        for (int r = 0; r < 16; r++) { s0[r] = 0.f; s1[r] = 0.f; }
        __builtin_amdgcn_s_setprio(1);
        #pragma unroll
        for (int ds = 0; ds < 4; ds++) {
            s16x8 k0 = *(const s16x8*)&Kb[ ln31       * 64 + ((ds * 16 + hi * 8) ^ swz)];
            s16x8 k1 = *(const s16x8*)&Kb[(32 + ln31) * 64 + ((ds * 16 + hi * 8) ^ swz)];
            s0 = mfma32(k0, qf[ds], s0);
            s1 = mfma32(k1, qf[ds], s1);
        }
        __builtin_amdgcn_s_setprio(0);

        // in-register online softmax (per-lane q-row; partner lane has other kv half)
        float tm = -1e30f;
        #pragma unroll
        for (int r = 0; r < 16; r++) tm = fmaxf(tm, fmaxf(s0[r], s1[r]));
        tm = fmaxf(tm, __shfl_xor(tm, 32));
        float mnew = fmaxf(mrun, tm);
        float al = __expf(mrun - mnew);
        mrun = mnew;
        float rs = 0.f;
        #pragma unroll
        for (int r = 0; r < 16; r++) { float p = __expf(s0[r] - mnew); s0[r] = p; rs += p; }
        #pragma unroll
        for (int r = 0; r < 16; r++) { float p = __expf(s1[r] - mnew); s1[r] = p; rs += p; }
        rs += __shfl_xor(rs, 32);
        lrun = lrun * al + rs;
        #pragma unroll
        for (int r = 0; r < 16; r++) { o0[r] *= al; o1[r] *= al; }

        // P -> bf16 B-operand frags in-register (cvt_pk + v_permlane32_swap_b32).
        // Own words: a,a2 = low-kv pairs; b,b2 = high-kv pairs.
        // Need: u0 = hi ? partner_b : own_a ; u2 = hi ? own_b : partner_a.
        // v_permlane32_swap_b32 a, b  (vdst.row1 <-> vsrc.row0) gives exactly that.
        s16x8 pa[4];
        #pragma unroll
        for (int ks = 0; ks < 4; ks++) {
            float x0, x1, x2, x3, x4, x5, x6, x7;
            if      (ks == 0) { x0=s0[0]; x1=s0[1]; x2=s0[2];  x3=s0[3];  x4=s0[4];  x5=s0[5];  x6=s0[6];  x7=s0[7];  }
            else if (ks == 1) { x0=s0[8]; x1=s0[9]; x2=s0[10]; x3=s0[11]; x4=s0[12]; x5=s0[13]; x6=s0[14]; x7=s0[15]; }
            else if (ks == 2) { x0=s1[0]; x1=s1[1]; x2=s1[2];  x3=s1[3];  x4=s1[4];  x5=s1[5];  x6=s1[6];  x7=s1[7];  }
            else              { x0=s1[8]; x1=s1[9]; x2=s1[10]; x3=s1[11]; x4=s1[12]; x5=s1[13]; x6=s1[14]; x7=s1[15]; }
            unsigned a  = cvtpk(x0, x1);
            unsigned a2 = cvtpk(x2, x3);
            unsigned b  = cvtpk(x4, x5);
            unsigned b2 = cvtpk(x6, x7);
            asm volatile("v_permlane32_swap_b32 %0, %1" : "+v"(a),  "+v"(b));
            asm volatile("v_permlane32_swap_b32 %0, %1" : "+v"(a2), "+v"(b2));
            union { s16x8 v; unsigned u[4]; } pu;
            pu.u[0] = a; pu.u[1] = a2; pu.u[2] = b; pu.u[3] = b2;
            pa[ks] = pu.v;
        }

        // PV (swapped): O^T[d][q] += Vt-frag x P^T-frag
        __builtin_amdgcn_s_setprio(1);
        #pragma unroll
        for (int ks = 0; ks < 4; ks++) {
            s16x8 v0 = *(const s16x8*)&Vb[ ln31       * 64 + ((ks * 16 + hi * 8) ^ swz)];
            s16x8 v1 = *(const s16x8*)&Vb[(32 + ln31) * 64 + ((ks * 16 + hi * 8) ^ swz)];
            o0 = mfma32(v0, pa[ks], o0);
            o1 = mfma32(v1, pa[ks], o1);
        }
        __builtin_amdgcn_s_setprio(0);

        __syncthreads();
        cur ^= 1;
    }

    // epilogue: divide by l, pack bf16 pairs, 8B stores
    float inv = 1.0f / lrun;
    const int b = bh >> 4, h = bh & 15;
    const int qg = q0 + w * 32 + ln31;
    size_t base = ((size_t)(b * 2048 + qg)) * 1024 + h * 64;
    #pragma unroll
    for (int dc = 0; dc < 2; dc++) {
        #pragma unroll
        for (int g = 0; g < 4; g++) {
            float y0, y1, y2, y3;
            if (dc == 0) { y0 = o0[4*g]; y1 = o0[4*g+1]; y2 = o0[4*g+2]; y3 = o0[4*g+3]; }
            else         { y0 = o1[4*g]; y1 = o1[4*g+1]; y2 = o1[4*g+2]; y3 = o1[4*g+3]; }
            unsigned lo  = cvtpk(y0 * inv, y1 * inv);
            unsigned hi2 = cvtpk(y2 * inv, y3 * inv);
            int d = dc * 32 + 8 * g + 4 * hi;
            uint2 stv; stv.x = lo; stv.y = hi2;
            *(uint2*)&AO[base + d] = stv;
        }
    }
}

// ---------- output projection GEMM: Out = AO * Wo^T (fp32 out) ----------
__global__ __launch_bounds__(256) void k_gemm_out(
    const unsigned short* __restrict__ AOb,
    const unsigned short* __restrict__ Wob,
    float* __restrict__ Out)
{
    __shared__ __attribute__((aligned(16))) unsigned short As[128 * 32];
    __shared__ __attribute__((aligned(16))) unsigned short Bs[128 * 32];
    const int tid = threadIdx.x;
    const int lane = tid & 63;
    const int w  = tid >> 6;
    const int wm = (w >> 1) * 64, wn = (w & 1) * 64;
    const int r  = lane & 15, rg = lane >> 4;
    const int m0 = blockIdx.x * 128, n0 = blockIdx.y * 128;

    f32x4 acc[4][4];
    const f32x4 zf = {0.f, 0.f, 0.f, 0.f};
    #pragma unroll
    for (int i = 0; i < 4; i++)
        #pragma unroll
        for (int j = 0; j < 4; j++) acc[i][j] = zf;

    const unsigned short* ga = AOb + (size_t)(m0 + (tid >> 2)) * 1024 + (tid & 3) * 8;
    const unsigned short* gb = Wob + (size_t)(n0 + (tid >> 2)) * 1024 + (tid & 3) * 8;

    for (int k0 = 0; k0 < 1024; k0 += 32) {
        gl_lds16(ga + k0,             As + tid * 8);
        gl_lds16(ga + k0 + 64 * 1024, As + 2048 + tid * 8);
        gl_lds16(gb + k0,             Bs + tid * 8);
        gl_lds16(gb + k0 + 64 * 1024, Bs + 2048 + tid * 8);
        __syncthreads();
        s16x8 af[4], bfr[4];
        #pragma unroll
        for (int mi = 0; mi < 4; mi++) af[mi]  = *(const s16x8*)&As[(wm + mi * 16 + r) * 32 + rg * 8];
        #pragma unroll
        for (int ni = 0; ni < 4; ni++) bfr[ni] = *(const s16x8*)&Bs[(wn + ni * 16 + r) * 32 + rg * 8];
        #pragma unroll
        for (int mi = 0; mi < 4; mi++)
            #pragma unroll
            for (int ni = 0; ni < 4; ni++)
                acc[mi][ni] = mfma16(af[mi], bfr[ni], acc[mi][ni]);
        __syncthreads();
    }

    #pragma unroll
    for (int mi = 0; mi < 4; mi++)
        #pragma unroll
        for (int ni = 0; ni < 4; ni++)
            #pragma unroll
            for (int rr = 0; rr < 4; rr++) {
                int m = m0 + wm + mi * 16 + rg * 4 + rr;
                int e = n0 + wn + ni * 16 + r;
                Out[(size_t)m * 1024 + e] = acc[mi][ni][rr];
            }
}

// ---------- launcher ----------
extern "C" void kernel_launch(void* const* d_in, const int* in_sizes, int n_in,
                              void* d_out, int out_size, void* d_ws, size_t ws_size,
                              hipStream_t stream) {
    const float* X  = (const float*)d_in[0];
    const float* Wq = (const float*)d_in[1];
    const float* Wk = (const float*)d_in[2];
    const float* Wv = (const float*)d_in[3];
    const float* Wo = (const float*)d_in[4];
    float* Out = (float*)d_out;
    char* ws = (char*)d_ws;

    unsigned short* Xb   = (unsigned short*)(ws);
    unsigned short* Wqb  = (unsigned short*)(ws + 8388608);
    unsigned short* Wkb  = (unsigned short*)(ws + 10485760);
    unsigned short* Wvb  = (unsigned short*)(ws + 12582912);
    unsigned short* Wob  = (unsigned short*)(ws + 14680064);
    unsigned short* Qb   = (unsigned short*)(ws + 16777216);
    unsigned short* Kb   = (unsigned short*)(ws + 25165824);
    unsigned short* Vtb  = (unsigned short*)(ws + 33554432);
    unsigned short* AOb  = (unsigned short*)(ws + 41943040);
    float*          cosT = (float*)(ws + 50331648);
    float*          sinT = (float*)(ws + 50855936);

    k_convert<<<4096, 256, 0, stream>>>(X,  Xb,  1048576);
    k_convert<<<1024, 256, 0, stream>>>(Wq, Wqb, 262144);
    k_convert<<<1024, 256, 0, stream>>>(Wk, Wkb, 262144);
    k_convert<<<1024, 256, 0, stream>>>(Wv, Wvb, 262144);
    k_convert<<<1024, 256, 0, stream>>>(Wo, Wob, 262144);
    k_rope_table<<<512, 256, 0, stream>>>(cosT, sinT);
    k_gemm_qkv<<<dim3(32, 8, 3), 256, 0, stream>>>(Xb, Wqb, Wkb, Wvb, cosT, sinT, Qb, Kb, Vtb);
    k_attn<<<dim3(8, 32), 512, 0, stream>>>(Qb, Kb, Vtb, AOb);
    k_gemm_out<<<dim3(32, 8), 256, 0, stream>>>(AOb, Wob, Out);
}

// Round 6
// 212.972 us; speedup vs baseline: 1.3214x; 1.0631x over previous
//
#include <hip/hip_runtime.h>

typedef __attribute__((ext_vector_type(4)))  float  f32x4;
typedef __attribute__((ext_vector_type(16))) float  f32x16;
typedef __attribute__((ext_vector_type(8)))  short  s16x8;

// ---------- helpers ----------
__device__ __forceinline__ unsigned short f2bf(float f) {
    union { float f; unsigned u; } v; v.f = f;
    unsigned u = v.u + 0x7fffu + ((v.u >> 16) & 1u);   // RNE
    return (unsigned short)(u >> 16);
}

__device__ __forceinline__ unsigned cvtpk(float lo, float hi_) {
    unsigned r;
    asm("v_cvt_pk_bf16_f32 %0, %1, %2" : "=v"(r) : "v"(lo), "v"(hi_));
    return r;
}

__device__ __forceinline__ float ex2(float x) {
#if __has_builtin(__builtin_amdgcn_exp2f)
    return __builtin_amdgcn_exp2f(x);
#else
    return exp2f(x);
#endif
}

__device__ __forceinline__ void gl_lds16(const unsigned short* g, unsigned short* l) {
    __builtin_amdgcn_global_load_lds(
        (const __attribute__((address_space(1))) void*)g,
        (__attribute__((address_space(3))) void*)l, 16, 0, 0);
}

__device__ __forceinline__ f32x4 mfma16(s16x8 a, s16x8 b, f32x4 c) {
    return __builtin_amdgcn_mfma_f32_16x16x32_bf16(a, b, c, 0, 0, 0);
}
__device__ __forceinline__ f32x16 mfma32(s16x8 a, s16x8 b, f32x16 c) {
    return __builtin_amdgcn_mfma_f32_32x32x16_bf16(a, b, c, 0, 0, 0);
}

// ---------- fused preamble: all fp32->bf16 converts + RoPE table, ONE launch ----------
// ranges: [0,1048576) X float4 | [1048576,2097152) weights | [2097152,2129920) rope
__global__ __launch_bounds__(256) void k_prep(
    const float* __restrict__ X,  const float* __restrict__ Wq,
    const float* __restrict__ Wk, const float* __restrict__ Wv,
    const float* __restrict__ Wo,
    unsigned short* __restrict__ Xb,  unsigned short* __restrict__ Wqb,
    unsigned short* __restrict__ Wkb, unsigned short* __restrict__ Wvb,
    unsigned short* __restrict__ Wob,
    float* __restrict__ ct, float* __restrict__ st)
{
    int i = blockIdx.x * 256 + threadIdx.x;
    if (i < 2097152) {
        const float* s; unsigned short* d; int o;
        if (i < 1048576) { s = X; d = Xb; o = i; }
        else {
            int j = i - 1048576;
            int wsel = j >> 18; o = j & 262143;
            s = (wsel == 0) ? Wq : (wsel == 1) ? Wk : (wsel == 2) ? Wv : Wo;
            d = (wsel == 0) ? Wqb : (wsel == 1) ? Wkb : (wsel == 2) ? Wvb : Wob;
        }
        float4 f = reinterpret_cast<const float4*>(s)[o];
        ushort4 u;
        u.x = f2bf(f.x); u.y = f2bf(f.y); u.z = f2bf(f.z); u.w = f2bf(f.w);
        reinterpret_cast<ushort4*>(d)[o] = u;
    } else {
        int j = i - 2097152;            // 0..32767 -> 4 table entries each
        int e0 = j << 2;
        int sq = e0 >> 6, d0 = e0 & 63;
        float4 cv, sv;
        #pragma unroll
        for (int k = 0; k < 4; k++) {
            int d = d0 + k;
            float invf = ex2(-(float)(d & 31) * 0.4152410118609203f); // 10000^{-(d&31)/32}
            float ang = (float)sq * invf;
            float ss, cc;
            sincosf(ang, &ss, &cc);
            ((float*)&cv)[k] = cc; ((float*)&sv)[k] = ss;
        }
        *(float4*)&ct[e0] = cv;
        *(float4*)&st[e0] = sv;
    }
}

// ---------- fused QKV projection GEMM (bf16 MFMA) ----------
// z=0: Q = X*Wq^T (+RoPE, *0.125*log2e) -> [B,H,S,D]   (log2-domain softmax)
// z=1: K = X*Wk^T (+RoPE)               -> [B,H,S,D]
// z=2: V^T = Wv*X^T                     -> [B,H,D,S]
__global__ __launch_bounds__(256) void k_gemm_qkv(
    const unsigned short* __restrict__ Xb,
    const unsigned short* __restrict__ Wqb,
    const unsigned short* __restrict__ Wkb,
    const unsigned short* __restrict__ Wvb,
    const float* __restrict__ ct, const float* __restrict__ st,
    unsigned short* __restrict__ Qo, unsigned short* __restrict__ Ko,
    unsigned short* __restrict__ Vt)
{
    __shared__ __attribute__((aligned(16))) unsigned short As[128 * 32];
    __shared__ __attribute__((aligned(16))) unsigned short Bs[128 * 32];
    const int z = blockIdx.z;
    const int tid = threadIdx.x;
    const int lane = tid & 63;
    const int w  = tid >> 6;
    const int wm = (w >> 1) * 64, wn = (w & 1) * 64;
    const int r  = lane & 15, rg = lane >> 4;

    const unsigned short *Ap, *Bp;
    int m0, n0;
    if (z < 2) { Ap = Xb;  Bp = z ? Wkb : Wqb; m0 = blockIdx.x * 128; n0 = blockIdx.y * 128; }
    else       { Ap = Wvb; Bp = Xb;            m0 = blockIdx.y * 128; n0 = blockIdx.x * 128; }

    f32x4 acc[4][4];
    const f32x4 zf = {0.f, 0.f, 0.f, 0.f};
    #pragma unroll
    for (int i = 0; i < 4; i++)
        #pragma unroll
        for (int j = 0; j < 4; j++) acc[i][j] = zf;

    const unsigned short* ga = Ap + (size_t)(m0 + (tid >> 2)) * 1024 + (tid & 3) * 8;
    const unsigned short* gb = Bp + (size_t)(n0 + (tid >> 2)) * 1024 + (tid & 3) * 8;

    for (int k0 = 0; k0 < 1024; k0 += 32) {
        gl_lds16(ga + k0,             As + tid * 8);
        gl_lds16(ga + k0 + 64 * 1024, As + 2048 + tid * 8);
        gl_lds16(gb + k0,             Bs + tid * 8);
        gl_lds16(gb + k0 + 64 * 1024, Bs + 2048 + tid * 8);
        __syncthreads();
        s16x8 af[4], bfr[4];
        #pragma unroll
        for (int mi = 0; mi < 4; mi++) af[mi]  = *(const s16x8*)&As[(wm + mi * 16 + r) * 32 + rg * 8];
        #pragma unroll
        for (int ni = 0; ni < 4; ni++) bfr[ni] = *(const s16x8*)&Bs[(wn + ni * 16 + r) * 32 + rg * 8];
        #pragma unroll
        for (int mi = 0; mi < 4; mi++)
            #pragma unroll
            for (int ni = 0; ni < 4; ni++)
                acc[mi][ni] = mfma16(af[mi], bfr[ni], acc[mi][ni]);
        __syncthreads();
    }

    if (z < 2) {
        unsigned short* Out = z ? Ko : Qo;
        // Q: fold 1/sqrt(64) * log2(e) so softmax runs in exp2 domain
        const float qscale = z ? 1.0f : 0.18033688011112042f;
        #pragma unroll
        for (int mi = 0; mi < 4; mi++)
            #pragma unroll
            for (int ni = 0; ni < 4; ni++)
                #pragma unroll
                for (int rr = 0; rr < 4; rr++) {
                    float v = acc[mi][ni][rr];
                    float vp = __shfl_xor(v, 1);
                    int m = m0 + wm + mi * 16 + rg * 4 + rr;
                    int e = n0 + wn + ni * 16 + r;
                    int s = m & 2047, d = e & 63;
                    float c = ct[(s << 6) + d], sn = st[(s << 6) + d];
                    float sgn = (e & 1) ? 1.0f : -1.0f;
                    v = fmaf(v, c, sgn * vp * sn) * qscale;
                    int b = m >> 11, h = e >> 6;
                    Out[(((size_t)(b * 16 + h) * 2048 + s) << 6) + d] = f2bf(v);
                }
    } else {
        #pragma unroll
        for (int mi = 0; mi < 4; mi++)
            #pragma unroll
            for (int ni = 0; ni < 4; ni++)
                #pragma unroll
                for (int rr = 0; rr < 4; rr++) {
                    int e  = m0 + wm + mi * 16 + rg * 4 + rr;
                    int mm = n0 + wn + ni * 16 + r;
                    int b = mm >> 11, s = mm & 2047, h = e >> 6, d = e & 63;
                    Vt[((size_t)(b * 16 + h) * 64 + d) * 2048 + s] = f2bf(acc[mi][ni][rr]);
                }
    }
}

// ---------- flash attention, 4-wave 32x32 swapped-operand, exp2-domain ----------
// Q,K: [B,H,S=2048,D=64] bf16 (Q pre-scaled by 0.125*log2e); Vt: [B,H,D,S] bf16
// AO:  [B*S, 1024] bf16.  grid (16,32), 256 thr (4 waves x 32 q = 128 q/block).
__global__ __launch_bounds__(256, 3) void k_attn(
    const unsigned short* __restrict__ Q,
    const unsigned short* __restrict__ K,
    const unsigned short* __restrict__ Vt,
    unsigned short* __restrict__ AO)
{
    __shared__ __attribute__((aligned(16))) unsigned short Ks[2][64 * 64];
    __shared__ __attribute__((aligned(16))) unsigned short Vs[2][64 * 64];
    const int bh = blockIdx.y;
    const int q0 = blockIdx.x * 128;
    const int tid = threadIdx.x, lane = tid & 63, w = tid >> 6;
    const int ln31 = lane & 31, hi = lane >> 5;
    const int swz = (ln31 & 7) << 3;            // element-index XOR (16B granules)
    const unsigned short* Qp = Q  + (size_t)bh * 2048 * 64;
    const unsigned short* Kp = K  + (size_t)bh * 2048 * 64;
    const unsigned short* Vp = Vt + (size_t)bh * 64 * 2048;

    // Q B-fragments: lane=q (ln31), k = ds*16 + hi*8 + j
    s16x8 qf[4];
    #pragma unroll
    for (int ds = 0; ds < 4; ds++)
        qf[ds] = *(const s16x8*)&Qp[(size_t)(q0 + w * 32 + ln31) * 64 + ds * 16 + hi * 8];

    f32x16 o0, o1;
    #pragma unroll
    for (int r = 0; r < 16; r++) { o0[r] = 0.f; o1[r] = 0.f; }
    float mrun = -1e30f, lrun = 0.f;

    // staging: 256 threads x 2 chunks per tensor; LDS linear, global pre-swizzled
    const int c1 = tid + 256;
    const int sr0 = tid >> 3, sc0 = ((tid & 7) * 8) ^ ((sr0 & 7) << 3);
    const int sr1 = c1 >> 3,  sc1 = ((c1 & 7) * 8) ^ ((sr1 & 7) << 3);
    const unsigned short* gk0 = Kp + (size_t)sr0 * 64   + sc0;
    const unsigned short* gk1 = Kp + (size_t)sr1 * 64   + sc1;
    const unsigned short* gv0 = Vp + (size_t)sr0 * 2048 + sc0;
    const unsigned short* gv1 = Vp + (size_t)sr1 * 2048 + sc1;
    const int t80 = tid * 8, t81 = c1 * 8;

    gl_lds16(gk0, &Ks[0][t80]);
    gl_lds16(gk1, &Ks[0][t81]);
    gl_lds16(gv0, &Vs[0][t80]);
    gl_lds16(gv1, &Vs[0][t81]);
    asm volatile("s_waitcnt vmcnt(0)" ::: "memory");
    __syncthreads();

    int cur = 0;
    for (int t = 0; t < 32; ++t) {
        if (t < 31) {  // stage next tile; the loop-end __syncthreads drains vmcnt
            size_t ok = (size_t)(t + 1) * 4096;
            size_t ov = (size_t)(t + 1) * 64;
            gl_lds16(gk0 + ok, &Ks[cur ^ 1][t80]);
            gl_lds16(gk1 + ok, &Ks[cur ^ 1][t81]);
            gl_lds16(gv0 + ov, &Vs[cur ^ 1][t80]);
            gl_lds16(gv1 + ov, &Vs[cur ^ 1][t81]);
        }
        const unsigned short* Kb = Ks[cur];
        const unsigned short* Vb = Vs[cur];

        // QK^T (swapped): S^T[kv][q]
        f32x16 s0, s1;
        #pragma unroll
        for (int r = 0; r < 16; r++) { s0[r] = 0.f; s1[r] = 0.f; }
        __builtin_amdgcn_s_setprio(1);
        #pragma unroll
        for (int ds = 0; ds < 4; ds++) {
            s16x8 k0 = *(const s16x8*)&Kb[ ln31       * 64 + ((ds * 16 + hi * 8) ^ swz)];
            s16x8 k1 = *(const s16x8*)&Kb[(32 + ln31) * 64 + ((ds * 16 + hi * 8) ^ swz)];
            s0 = mfma32(k0, qf[ds], s0);
            s1 = mfma32(k1, qf[ds], s1);
        }
        __builtin_amdgcn_s_setprio(0);

        // online softmax, exp2 domain, defer-max (skip rescale if max grew < 8)
        float tm = -1e30f;
        #pragma unroll
        for (int r = 0; r < 16; r++) tm = fmaxf(tm, fmaxf(s0[r], s1[r]));
        tm = fmaxf(tm, __shfl_xor(tm, 32));
        if (!__all(tm <= mrun + 8.0f)) {
            float mnew = fmaxf(mrun, tm);
            float al = ex2(mrun - mnew);
            mrun = mnew;
            lrun *= al;
            #pragma unroll
            for (int r = 0; r < 16; r++) { o0[r] *= al; o1[r] *= al; }
        }
        float rs = 0.f;
        #pragma unroll
        for (int r = 0; r < 16; r++) { float p = ex2(s0[r] - mrun); s0[r] = p; rs += p; }
        #pragma unroll
        for (int r = 0; r < 16; r++) { float p = ex2(s1[r] - mrun); s1[r] = p; rs += p; }
        rs += __shfl_xor(rs, 32);
        lrun += rs;

        // P -> bf16 B-operand frags in-register (cvt_pk + v_permlane32_swap_b32).
        // u0 = hi ? partner_b : own_a ; u2 = hi ? own_b : partner_a.
        s16x8 pa[4];
        #pragma unroll
        for (int ks = 0; ks < 4; ks++) {
            float x0, x1, x2, x3, x4, x5, x6, x7;
            if      (ks == 0) { x0=s0[0]; x1=s0[1]; x2=s0[2];  x3=s0[3];  x4=s0[4];  x5=s0[5];  x6=s0[6];  x7=s0[7];  }
            else if (ks == 1) { x0=s0[8]; x1=s0[9]; x2=s0[10]; x3=s0[11]; x4=s0[12]; x5=s0[13]; x6=s0[14]; x7=s0[15]; }
            else if (ks == 2) { x0=s1[0]; x1=s1[1]; x2=s1[2];  x3=s1[3];  x4=s1[4];  x5=s1[5];  x6=s1[6];  x7=s1[7];  }
            else              { x0=s1[8]; x1=s1[9]; x2=s1[10]; x3=s1[11]; x4=s1[12]; x5=s1[13]; x6=s1[14]; x7=s1[15]; }
            unsigned a  = cvtpk(x0, x1);
            unsigned a2 = cvtpk(x2, x3);
            unsigned b  = cvtpk(x4, x5);
            unsigned b2 = cvtpk(x6, x7);
            asm volatile("v_permlane32_swap_b32 %0, %1" : "+v"(a),  "+v"(b));
            asm volatile("v_permlane32_swap_b32 %0, %1" : "+v"(a2), "+v"(b2));
            union { s16x8 v; unsigned u[4]; } pu;
            pu.u[0] = a; pu.u[1] = a2; pu.u[2] = b; pu.u[3] = b2;
            pa[ks] = pu.v;
        }

        // PV (swapped): O^T[d][q] += Vt-frag x P^T-frag
        __builtin_amdgcn_s_setprio(1);
        #pragma unroll
        for (int ks = 0; ks < 4; ks++) {
            s16x8 v0 = *(const s16x8*)&Vb[ ln31       * 64 + ((ks * 16 + hi * 8) ^ swz)];
            s16x8 v1 = *(const s16x8*)&Vb[(32 + ln31) * 64 + ((ks * 16 + hi * 8) ^ swz)];
            o0 = mfma32(v0, pa[ks], o0);
            o1 = mfma32(v1, pa[ks], o1);
        }
        __builtin_amdgcn_s_setprio(0);

        __syncthreads();
        cur ^= 1;
    }

    // epilogue: divide by l, pack bf16 pairs, 8B stores
    float inv = 1.0f / lrun;
    const int b = bh >> 4, h = bh & 15;
    const int qg = q0 + w * 32 + ln31;
    size_t base = ((size_t)(b * 2048 + qg)) * 1024 + h * 64;
    #pragma unroll
    for (int dc = 0; dc < 2; dc++) {
        #pragma unroll
        for (int g = 0; g < 4; g++) {
            float y0, y1, y2, y3;
            if (dc == 0) { y0 = o0[4*g]; y1 = o0[4*g+1]; y2 = o0[4*g+2]; y3 = o0[4*g+3]; }
            else         { y0 = o1[4*g]; y1 = o1[4*g+1]; y2 = o1[4*g+2]; y3 = o1[4*g+3]; }
            unsigned lo  = cvtpk(y0 * inv, y1 * inv);
            unsigned hi2 = cvtpk(y2 * inv, y3 * inv);
            int d = dc * 32 + 8 * g + 4 * hi;
            uint2 stv; stv.x = lo; stv.y = hi2;
            *(uint2*)&AO[base + d] = stv;
        }
    }
}

// ---------- output projection GEMM: Out = AO * Wo^T (fp32 out) ----------
__global__ __launch_bounds__(256) void k_gemm_out(
    const unsigned short* __restrict__ AOb,
    const unsigned short* __restrict__ Wob,
    float* __restrict__ Out)
{
    __shared__ __attribute__((aligned(16))) unsigned short As[128 * 32];
    __shared__ __attribute__((aligned(16))) unsigned short Bs[128 * 32];
    const int tid = threadIdx.x;
    const int lane = tid & 63;
    const int w  = tid >> 6;
    const int wm = (w >> 1) * 64, wn = (w & 1) * 64;
    const int r  = lane & 15, rg = lane >> 4;
    const int m0 = blockIdx.x * 128, n0 = blockIdx.y * 128;

    f32x4 acc[4][4];
    const f32x4 zf = {0.f, 0.f, 0.f, 0.f};
    #pragma unroll
    for (int i = 0; i < 4; i++)
        #pragma unroll
        for (int j = 0; j < 4; j++) acc[i][j] = zf;

    const unsigned short* ga = AOb + (size_t)(m0 + (tid >> 2)) * 1024 + (tid & 3) * 8;
    const unsigned short* gb = Wob + (size_t)(n0 + (tid >> 2)) * 1024 + (tid & 3) * 8;

    for (int k0 = 0; k0 < 1024; k0 += 32) {
        gl_lds16(ga + k0,             As + tid * 8);
        gl_lds16(ga + k0 + 64 * 1024, As + 2048 + tid * 8);
        gl_lds16(gb + k0,             Bs + tid * 8);
        gl_lds16(gb + k0 + 64 * 1024, Bs + 2048 + tid * 8);
        __syncthreads();
        s16x8 af[4], bfr[4];
        #pragma unroll
        for (int mi = 0; mi < 4; mi++) af[mi]  = *(const s16x8*)&As[(wm + mi * 16 + r) * 32 + rg * 8];
        #pragma unroll
        for (int ni = 0; ni < 4; ni++) bfr[ni] = *(const s16x8*)&Bs[(wn + ni * 16 + r) * 32 + rg * 8];
        #pragma unroll
        for (int mi = 0; mi < 4; mi++)
            #pragma unroll
            for (int ni = 0; ni < 4; ni++)
                acc[mi][ni] = mfma16(af[mi], bfr[ni], acc[mi][ni]);
        __syncthreads();
    }

    #pragma unroll
    for (int mi = 0; mi < 4; mi++)
        #pragma unroll
        for (int ni = 0; ni < 4; ni++)
            #pragma unroll
            for (int rr = 0; rr < 4; rr++) {
                int m = m0 + wm + mi * 16 + rg * 4 + rr;
                int e = n0 + wn + ni * 16 + r;
                Out[(size_t)m * 1024 + e] = acc[mi][ni][rr];
            }
}

// ---------- launcher ----------
extern "C" void kernel_launch(void* const* d_in, const int* in_sizes, int n_in,
                              void* d_out, int out_size, void* d_ws, size_t ws_size,
                              hipStream_t stream) {
    const float* X  = (const float*)d_in[0];
    const float* Wq = (const float*)d_in[1];
    const float* Wk = (const float*)d_in[2];
    const float* Wv = (const float*)d_in[3];
    const float* Wo = (const float*)d_in[4];
    float* Out = (float*)d_out;
    char* ws = (char*)d_ws;

    unsigned short* Xb   = (unsigned short*)(ws);
    unsigned short* Wqb  = (unsigned short*)(ws + 8388608);
    unsigned short* Wkb  = (unsigned short*)(ws + 10485760);
    unsigned short* Wvb  = (unsigned short*)(ws + 12582912);
    unsigned short* Wob  = (unsigned short*)(ws + 14680064);
    unsigned short* Qb   = (unsigned short*)(ws + 16777216);
    unsigned short* Kb   = (unsigned short*)(ws + 25165824);
    unsigned short* Vtb  = (unsigned short*)(ws + 33554432);
    unsigned short* AOb  = (unsigned short*)(ws + 41943040);
    float*          cosT = (float*)(ws + 50331648);
    float*          sinT = (float*)(ws + 50855936);

    k_prep<<<8320, 256, 0, stream>>>(X, Wq, Wk, Wv, Wo, Xb, Wqb, Wkb, Wvb, Wob, cosT, sinT);
    k_gemm_qkv<<<dim3(32, 8, 3), 256, 0, stream>>>(Xb, Wqb, Wkb, Wvb, cosT, sinT, Qb, Kb, Vtb);
    k_attn<<<dim3(16, 32), 256, 0, stream>>>(Qb, Kb, Vtb, AOb);
    k_gemm_out<<<dim3(32, 8), 256, 0, stream>>>(AOb, Wob, Out);
}